// Round 11
// baseline (214.177 us; speedup 1.0000x reference)
//
#include <hip/hip_runtime.h>
#include <hip/hip_bf16.h>

typedef __bf16 bf16x8 __attribute__((ext_vector_type(8)));
typedef float f32x4 __attribute__((ext_vector_type(4)));
typedef float f32x16 __attribute__((ext_vector_type(16)));

#define B_ 8
#define C_ 256
#define CI 128
#define N_ 4096

__device__ __forceinline__ float exp2fast(float x) {
    return __builtin_amdgcn_exp2f(x);   // v_exp_f32: 2^x
}
__device__ __forceinline__ ushort f2bf(float f) {
    union { float f; unsigned u; } v; v.f = f;
    unsigned r = v.u + 0x7fffu + ((v.u >> 16) & 1u);
    return (ushort)(r >> 16);
}
__device__ __forceinline__ float bf2f(ushort u) {
    union { unsigned u; float f; } v; v.u = ((unsigned)u) << 16;
    return v.f;
}
__device__ __forceinline__ unsigned cvtpk(float lo, float hi) {
    unsigned r;
    asm("v_cvt_pk_bf16_f32 %0, %1, %2" : "=v"(r) : "v"(lo), "v"(hi));
    return r;
}
__device__ __forceinline__ void plswap(unsigned& a, unsigned& b) {
    asm volatile("v_permlane32_swap_b32 %0, %1" : "+v"(a), "+v"(b));
}
__device__ __forceinline__ void gld16(const void* src, void* dst) {
    __builtin_amdgcn_global_load_lds(
        (const __attribute__((address_space(1))) unsigned*)src,
        (__attribute__((address_space(3))) unsigned*)dst, 16, 0, 0);
}

// ---------------- kernel 1: weight conversion ----------------
__global__ void k_prep(const float* __restrict__ tw, const float* __restrict__ pw,
                       const float* __restrict__ gw, const float* __restrict__ ow,
                       ushort* __restrict__ wbf, ushort* __restrict__ owbf) {
    int idx = blockIdx.x * 256 + threadIdx.x;
    if (idx < 384 * 256) {
        int i = idx >> 8, c = idx & 255;
        float v = (i < 128) ? tw[i * 256 + c]
                : (i < 256) ? pw[(i - 128) * 256 + c]
                            : gw[(i - 256) * 256 + c];
        wbf[idx] = f2bf(v);
    }
    if (idx < 256 * 128) owbf[idx] = f2bf(ow[idx]);
}

// ---------------- kernel 2: x -> xt[b][n][c] bf16 ----------------
__global__ __launch_bounds__(256) void k_transpose(const float* __restrict__ x,
                                                   ushort* __restrict__ xt) {
    __shared__ __align__(16) float tile[64][65];
    int b = blockIdx.z, c0 = blockIdx.y * 64, n0 = blockIdx.x * 64;
    int t = threadIdx.x;
    int cl = t >> 2, nc = (t & 3) * 16;
    const float* src = x + ((size_t)(b * 256 + c0 + cl)) * N_ + n0 + nc;
#pragma unroll
    for (int j = 0; j < 4; j++) {
        float4 v = *reinterpret_cast<const float4*>(src + 4 * j);
        tile[cl][nc + 4 * j + 0] = v.x;
        tile[cl][nc + 4 * j + 1] = v.y;
        tile[cl][nc + 4 * j + 2] = v.z;
        tile[cl][nc + 4 * j + 3] = v.w;
    }
    __syncthreads();
    int nl = t >> 2, cc = (t & 3) * 16;
    ushort* dst = xt + ((size_t)b * N_ + n0 + nl) * 256 + c0 + cc;
#pragma unroll
    for (int j = 0; j < 4; j++) {
        ushort4 o;
        o.x = f2bf(tile[cc + 4 * j + 0][nl]);
        o.y = f2bf(tile[cc + 4 * j + 1][nl]);
        o.z = f2bf(tile[cc + 4 * j + 2][nl]);
        o.w = f2bf(tile[cc + 4 * j + 3][nl]);
        *reinterpret_cast<ushort4*>(dst + 4 * j) = o;
    }
}

// ---------------- kernel 3: QKV GEMM ----------------
// it=0 -> theta*scale*log2e -> qt[n][c]; it=1 -> phi -> kt[n][c];
// it=2 -> g -> gvt TILED layout: [b][mt=n/32][chunk 0..511][16B] with
//   chunk(c, slot=(n%32)/8) = (c&7) | (slot<<3) | ((c>>3)<<5), elem = n%8.
__global__ __launch_bounds__(256) void k_qkv(const ushort* __restrict__ wbf,
                                             const ushort* __restrict__ xt,
                                             const float* __restrict__ tb,
                                             const float* __restrict__ pb,
                                             const float* __restrict__ gb,
                                             ushort* __restrict__ qt,
                                             ushort* __restrict__ kt,
                                             ushort* __restrict__ gv) {
    __shared__ __align__(16) ushort lt[4][64][72];
    int nt = blockIdx.x, it = blockIdx.y, b = blockIdx.z;
    int tid = threadIdx.x, w = tid >> 6, l = tid & 63, lr = l & 15, lg = l >> 4;
    int i_off = it * 128 + (w >> 1) * 64;
    int n_off = nt * 128 + (w & 1) * 64;
    const ushort* xb = xt + (size_t)b * N_ * 256;

    f32x4 acc[4][4];
#pragma unroll
    for (int i = 0; i < 4; i++)
#pragma unroll
        for (int j = 0; j < 4; j++) acc[i][j] = (f32x4)0.0f;

#pragma unroll
    for (int kc = 0; kc < 8; kc++) {
        int ko = kc * 32 + lg * 8;
        bf16x8 a[4], bb[4];
#pragma unroll
        for (int fi = 0; fi < 4; fi++)
            a[fi] = *reinterpret_cast<const bf16x8*>(wbf + (size_t)(i_off + fi * 16 + lr) * 256 + ko);
#pragma unroll
        for (int fn = 0; fn < 4; fn++)
            bb[fn] = *reinterpret_cast<const bf16x8*>(xb + (size_t)(n_off + fn * 16 + lr) * 256 + ko);
#pragma unroll
        for (int fi = 0; fi < 4; fi++)
#pragma unroll
            for (int fn = 0; fn < 4; fn++)
                acc[fi][fn] = __builtin_amdgcn_mfma_f32_16x16x32_bf16(a[fi], bb[fn], acc[fi][fn], 0, 0, 0);
    }

    const float* bias = (it == 0) ? tb : (it == 1) ? pb : gb;
    // fold 1/sqrt(128) * log2(e) into theta so attention can use exp2
    const float mul = (it == 0) ? (0.08838834764831845f * 1.4426950408889634f) : 1.0f;
    if (it == 2) {
        char* g = (char*)(gv + (size_t)b * CI * N_);   // tiled per batch: 128 tiles x 8192 B
#pragma unroll
        for (int fi = 0; fi < 4; fi++)
#pragma unroll
            for (int reg = 0; reg < 4; reg++) {
                int cl = (w >> 1) * 64 + fi * 16 + lg * 4 + reg;
                float bv = bias[cl];
                int cbyte = (cl & 7) * 16 + (cl >> 3) * 512;
#pragma unroll
                for (int fn = 0; fn < 4; fn++) {
                    int n = n_off + fn * 16 + lr;
                    size_t byte = (size_t)(n >> 5) * 8192 + cbyte
                                + ((n >> 3) & 3) * 128 + (n & 7) * 2;
                    *(ushort*)(g + byte) = f2bf(acc[fi][fn][reg] + bv);
                }
            }
    } else {
#pragma unroll
        for (int fi = 0; fi < 4; fi++)
#pragma unroll
            for (int reg = 0; reg < 4; reg++) {
                int il = fi * 16 + lg * 4 + reg;
                float bv = bias[(w >> 1) * 64 + il];
#pragma unroll
                for (int fn = 0; fn < 4; fn++)
                    lt[w][fn * 16 + lr][il] = f2bf((acc[fi][fn][reg] + bv) * mul);
            }
        __builtin_amdgcn_s_waitcnt(0);
        ushort* dst = ((it == 0) ? qt : kt) + (size_t)b * N_ * CI;
        ushort* drow = dst + (size_t)(n_off + l) * CI + (w >> 1) * 64;
#pragma unroll
        for (int cc = 0; cc < 8; cc++) {
            uint4 v = *reinterpret_cast<uint4*>(&lt[w][l][cc * 8]);
            *reinterpret_cast<uint4*>(drow + cc * 8) = v;
        }
    }
}

// ---------------- kernel 4: flash attention, 64 q-rows/wave, 2 blocks/CU ----------
// qt,kt: [b][n][128] (qt pre-scaled); gv: TILED (see k_qkv); yt: [b][n][128]
// 256 blocks x 256 threads, LDS EXACTLY 64KB -> 2 blocks/CU (2 waves/SIMD, the
// r8-proven TLP) AND 2-chain K/V fragment reuse (r10's halved LDS traffic).
// Wave (p=w>>1, s=w&1): KV half p (64 iters of KVBLK=32), q-rows qb*128+s*64..+63
// as two 32-q chains. Merge publishes acc0/acc1 in TWO rounds through a 34816B
// scratch (stride 68 f32 = 17 granules, conflict-free) reusing dead K/V space.
__global__ __launch_bounds__(256, 2) void k_attn(const ushort* __restrict__ qt,
                                                 const ushort* __restrict__ kt,
                                                 const ushort* __restrict__ gv,
                                                 ushort* __restrict__ yt) {
    __shared__ __align__(16) char smem[65536];
    int bid = blockIdx.x;
    int b = bid & 7, qb = bid >> 3;  // batch -> XCD affinity
    int tid = threadIdx.x, w = tid >> 6, l = tid & 63;
    int p = w >> 1, s = w & 1;
    int l31 = l & 31, lh = l >> 5;
    const ushort* qtb = qt + (size_t)b * N_ * CI;
    const ushort* ktb = kt + (size_t)b * N_ * CI;
    const ushort* gvb = gv + (size_t)b * CI * N_;
    char* kbuf = smem + p * 16384;           // [buf][32 m][256 B]  XOR-swizzled
    char* vbuf = smem + 32768 + p * 16384;   // [buf][512 chunks of 16B] tiled image
    const int pbase = p * 2048;
    const int nq = qb * 128 + s * 64;
    const int q0 = nq + l31, q1 = nq + 32 + l31;
    const int swk = (l31 & 7) << 4;
    const int vrb = (l31 & 7) * 16 + lh * 128 + (l31 >> 3) * 512;  // + mk*256 + fc*2048

    // Q fragments for both 32-q chains
    bf16x8 qf0[8], qf1[8];
#pragma unroll
    for (int kc = 0; kc < 8; kc++) {
        qf0[kc] = *reinterpret_cast<const bf16x8*>(qtb + (size_t)q0 * CI + kc * 16 + lh * 8);
        qf1[kc] = *reinterpret_cast<const bf16x8*>(qtb + (size_t)q1 * CI + kc * 16 + lh * 8);
    }

    f32x16 acc0[4], acc1[4];
#pragma unroll
    for (int fc = 0; fc < 4; fc++) { acc0[fc] = (f32x16)0.0f; acc1[fc] = (f32x16)0.0f; }
    float lr0 = 0.f, lr1 = 0.f;

#define STAGE(t_, bi)                                                              \
    do {                                                                           \
        int m0_ = pbase + (t_) * 32;                                               \
        const char* ks_ = (const char*)(ktb + (size_t)m0_ * CI);                   \
        const char* vs_ = (const char*)gvb + (size_t)m0_ * 256;                    \
        char* kd_ = kbuf + (bi) * 8192;                                            \
        char* vd_ = vbuf + (bi) * 8192;                                            \
        _Pragma("unroll")                                                          \
        for (int i_ = 0; i_ < 4; ++i_) {                                           \
            int cc = i_ * 128 + s * 64 + l;                                        \
            int m_ = cc >> 4, hb = (cc & 15) << 4;                                 \
            gld16(ks_ + m_ * 256 + (hb ^ ((m_ & 7) << 4)), kd_ + cc * 16);         \
        }                                                                          \
        _Pragma("unroll")                                                          \
        for (int i_ = 0; i_ < 4; ++i_) {                                           \
            int cc = i_ * 128 + s * 64 + l;                                        \
            gld16(vs_ + cc * 16, vd_ + cc * 16);                                   \
        }                                                                          \
    } while (0)

    STAGE(0, 0);
    __syncthreads();

    for (int t = 0; t < 64; ++t) {
        int cur = t & 1;
        if (t < 63) STAGE(t + 1, cur ^ 1);
        const char* kbc = kbuf + cur * 8192;
        const char* vbc = vbuf + cur * 8192;

        // ---- QK^T: each kf read feeds both q-chains ----
        f32x16 S0 = (f32x16)0.0f, S1 = (f32x16)0.0f;
        __builtin_amdgcn_s_setprio(1);
#pragma unroll
        for (int kc = 0; kc < 8; kc++) {
            bf16x8 kf = *reinterpret_cast<const bf16x8*>(
                kbc + l31 * 256 + ((kc * 32 + lh * 16) ^ swk));
            S0 = __builtin_amdgcn_mfma_f32_32x32x16_bf16(kf, qf0[kc], S0, 0, 0, 0);
            S1 = __builtin_amdgcn_mfma_f32_32x32x16_bf16(kf, qf1[kc], S1, 0, 0, 0);
        }
        __builtin_amdgcn_s_setprio(0);

        // ---- softmax (no max tracking), chain 0 then chain 1 ----
        union { unsigned u[4]; bf16x8 v; } p00, p01, p10, p11;
        {
            float pv[16];
            float rs = 0.f;
#pragma unroll
            for (int r = 0; r < 16; r++) { pv[r] = exp2fast(S0[r]); rs += pv[r]; }
            lr0 += rs;
            unsigned u0 = cvtpk(pv[0], pv[1]),  u1 = cvtpk(pv[2], pv[3]);
            unsigned u2 = cvtpk(pv[4], pv[5]),  u3 = cvtpk(pv[6], pv[7]);
            unsigned u4 = cvtpk(pv[8], pv[9]),  u5 = cvtpk(pv[10], pv[11]);
            unsigned u6 = cvtpk(pv[12], pv[13]), u7 = cvtpk(pv[14], pv[15]);
            plswap(u0, u2); plswap(u1, u3); plswap(u4, u6); plswap(u5, u7);
            p00.u[0] = u0; p00.u[1] = u1; p00.u[2] = u2; p00.u[3] = u3;
            p01.u[0] = u4; p01.u[1] = u5; p01.u[2] = u6; p01.u[3] = u7;
        }
        {
            float pv[16];
            float rs = 0.f;
#pragma unroll
            for (int r = 0; r < 16; r++) { pv[r] = exp2fast(S1[r]); rs += pv[r]; }
            lr1 += rs;
            unsigned u0 = cvtpk(pv[0], pv[1]),  u1 = cvtpk(pv[2], pv[3]);
            unsigned u2 = cvtpk(pv[4], pv[5]),  u3 = cvtpk(pv[6], pv[7]);
            unsigned u4 = cvtpk(pv[8], pv[9]),  u5 = cvtpk(pv[10], pv[11]);
            unsigned u6 = cvtpk(pv[12], pv[13]), u7 = cvtpk(pv[14], pv[15]);
            plswap(u0, u2); plswap(u1, u3); plswap(u4, u6); plswap(u5, u7);
            p10.u[0] = u0; p10.u[1] = u1; p10.u[2] = u2; p10.u[3] = u3;
            p11.u[0] = u4; p11.u[1] = u5; p11.u[2] = u6; p11.u[3] = u7;
        }

        // ---- PV: each vf read feeds both q-chains ----
        __builtin_amdgcn_s_setprio(1);
#pragma unroll
        for (int mk = 0; mk < 2; mk++) {
            bf16x8 pf0 = mk ? p01.v : p00.v;
            bf16x8 pf1 = mk ? p11.v : p10.v;
#pragma unroll
            for (int fc = 0; fc < 4; fc++) {
                bf16x8 vf = *reinterpret_cast<const bf16x8*>(vbc + vrb + mk * 256 + fc * 2048);
                acc0[fc] = __builtin_amdgcn_mfma_f32_32x32x16_bf16(vf, pf0, acc0[fc], 0, 0, 0);
                acc1[fc] = __builtin_amdgcn_mfma_f32_32x32x16_bf16(vf, pf1, acc1[fc], 0, 0, 0);
            }
        }
        __builtin_amdgcn_s_setprio(0);
        __syncthreads();
    }
#undef STAGE

    // complete softmax denominators across the two lane-halves
    lr0 += __shfl_xor(lr0, 32);
    lr1 += __shfl_xor(lr1, 32);

    // ---- split-KV merge, TWO rounds (chain 0 then chain 1) through 34816B ----
    // pub: [2 s][64 lanes][68 f32] (17 x 16B granules -> conflict-free);
    // mlb: [2 s][64 q] at +34816.
    float* pub = (float*)smem;
    float* mlb = (float*)(smem + 34816);
    __syncthreads();   // all waves done with K/V buffers before reuse
    if (p == 0 && lh == 0) {
        mlb[s * 64 + l31] = lr0;
        mlb[s * 64 + 32 + l31] = lr1;
    }
    if (p == 0) {
        float* ab = pub + (size_t)(s * 64 + l) * 68;
#pragma unroll
        for (int fc = 0; fc < 4; fc++)
            *reinterpret_cast<f32x16*>(ab + fc * 16) = acc0[fc];
    }
    __syncthreads();
    if (p == 1) {
        float inv0 = 1.f / (lr0 + mlb[s * 64 + l31]);
        const float* ab = pub + (size_t)(s * 64 + l) * 68;
        ushort* yb0 = yt + ((size_t)b * N_ + q0) * CI;
#pragma unroll
        for (int fc = 0; fc < 4; fc++) {
            f32x16 a0 = *reinterpret_cast<const f32x16*>(ab + fc * 16);
#pragma unroll
            for (int rg = 0; rg < 4; rg++) {
                ushort4 o;
                o.x = f2bf((acc0[fc][rg * 4 + 0] + a0[rg * 4 + 0]) * inv0);
                o.y = f2bf((acc0[fc][rg * 4 + 1] + a0[rg * 4 + 1]) * inv0);
                o.z = f2bf((acc0[fc][rg * 4 + 2] + a0[rg * 4 + 2]) * inv0);
                o.w = f2bf((acc0[fc][rg * 4 + 3] + a0[rg * 4 + 3]) * inv0);
                *reinterpret_cast<ushort4*>(yb0 + fc * 32 + rg * 8 + lh * 4) = o;
            }
        }
    }
    __syncthreads();
    if (p == 0) {
        float* ab = pub + (size_t)(s * 64 + l) * 68;
#pragma unroll
        for (int fc = 0; fc < 4; fc++)
            *reinterpret_cast<f32x16*>(ab + fc * 16) = acc1[fc];
    }
    __syncthreads();
    if (p == 1) {
        float inv1 = 1.f / (lr1 + mlb[s * 64 + 32 + l31]);
        const float* ab = pub + (size_t)(s * 64 + l) * 68;
        ushort* yb1 = yt + ((size_t)b * N_ + q1) * CI;
#pragma unroll
        for (int fc = 0; fc < 4; fc++) {
            f32x16 a1 = *reinterpret_cast<const f32x16*>(ab + fc * 16);
#pragma unroll
            for (int rg = 0; rg < 4; rg++) {
                ushort4 o;
                o.x = f2bf((acc1[fc][rg * 4 + 0] + a1[rg * 4 + 0]) * inv1);
                o.y = f2bf((acc1[fc][rg * 4 + 1] + a1[rg * 4 + 1]) * inv1);
                o.z = f2bf((acc1[fc][rg * 4 + 2] + a1[rg * 4 + 2]) * inv1);
                o.w = f2bf((acc1[fc][rg * 4 + 3] + a1[rg * 4 + 3]) * inv1);
                *reinterpret_cast<ushort4*>(yb1 + fc * 32 + rg * 8 + lh * 4) = o;
            }
        }
    }
}

// ---------------- kernel 5: out conv + partial BN sums (pre in bf16) ----------------
__global__ __launch_bounds__(256) void k_outconv(const ushort* __restrict__ owbf,
                                                 const ushort* __restrict__ yt,
                                                 const float* __restrict__ ob,
                                                 ushort* __restrict__ pre,
                                                 float* __restrict__ part) {
    int nt = blockIdx.x, ot = blockIdx.y, b = blockIdx.z;
    int tid = threadIdx.x, w = tid >> 6, l = tid & 63, lr = l & 15, lg = l >> 4;
    int o_off = ot * 128 + (w >> 1) * 64;
    int n_off = nt * 128 + (w & 1) * 64;
    const ushort* yb = yt + (size_t)b * N_ * CI;

    f32x4 acc[4][4];
#pragma unroll
    for (int i = 0; i < 4; i++)
#pragma unroll
        for (int j = 0; j < 4; j++) acc[i][j] = (f32x4)0.0f;

#pragma unroll
    for (int kc = 0; kc < 4; kc++) {
        int ko = kc * 32 + lg * 8;
        bf16x8 a[4], bb[4];
#pragma unroll
        for (int fo = 0; fo < 4; fo++)
            a[fo] = *reinterpret_cast<const bf16x8*>(owbf + (size_t)(o_off + fo * 16 + lr) * CI + ko);
#pragma unroll
        for (int fn = 0; fn < 4; fn++)
            bb[fn] = *reinterpret_cast<const bf16x8*>(yb + (size_t)(n_off + fn * 16 + lr) * CI + ko);
#pragma unroll
        for (int fo = 0; fo < 4; fo++)
#pragma unroll
            for (int fn = 0; fn < 4; fn++)
                acc[fo][fn] = __builtin_amdgcn_mfma_f32_16x16x32_bf16(a[fo], bb[fn], acc[fo][fn], 0, 0, 0);
    }

    ushort* pb_ = pre + (size_t)b * C_ * N_;
#pragma unroll
    for (int fo = 0; fo < 4; fo++)
#pragma unroll
        for (int reg = 0; reg < 4; reg++) {
            int o = o_off + fo * 16 + lg * 4 + reg;
            float bv = ob[o];
            float s1 = 0.f, s2 = 0.f;
#pragma unroll
            for (int fn = 0; fn < 4; fn++) {
                float v = acc[fo][fn][reg] + bv;
                pb_[(size_t)o * N_ + n_off + fn * 16 + lr] = f2bf(v);
                s1 += v;
                s2 += v * v;
            }
#pragma unroll
            for (int d = 1; d < 16; d <<= 1) {
                s1 += __shfl_xor(s1, d);
                s2 += __shfl_xor(s2, d);
            }
            if (lr == 0) {
                int slot = (b * 32 + nt) * 2 + (w & 1);
                part[((size_t)o * 512 + slot) * 2 + 0] = s1;
                part[((size_t)o * 512 + slot) * 2 + 1] = s2;
            }
        }
}

// ---------------- kernel 6: reduce BN stats ----------------
__global__ void k_stats(const float* __restrict__ part, const float* __restrict__ gamma,
                        const float* __restrict__ beta, float* __restrict__ stats) {
    int o = blockIdx.x, t = threadIdx.x;
    __shared__ float r1[256], r2[256];
    float s1 = part[((size_t)o * 512 + t) * 2 + 0] + part[((size_t)o * 512 + t + 256) * 2 + 0];
    float s2 = part[((size_t)o * 512 + t) * 2 + 1] + part[((size_t)o * 512 + t + 256) * 2 + 1];
    r1[t] = s1; r2[t] = s2;
    __syncthreads();
    for (int s = 128; s > 0; s >>= 1) {
        if (t < s) { r1[t] += r1[t + s]; r2[t] += r2[t + s]; }
        __syncthreads();
    }
    if (t == 0) {
        float cnt = 1.f / (float)(B_ * N_);
        float mean = r1[0] * cnt;
        float var = r2[0] * cnt - mean * mean;
        float inv = rsqrtf(var + 1e-5f);
        float a = gamma[o] * inv;
        stats[o * 2 + 0] = a;
        stats[o * 2 + 1] = beta[o] - mean * a;
    }
}

// ---------------- kernel 7: finalize ----------------
__global__ void k_final(const float* __restrict__ x, const ushort* __restrict__ pre,
                        const float* __restrict__ stats, float* __restrict__ out) {
    int idx = blockIdx.x * 256 + threadIdx.x;  // 4 elems each
    int o = (idx >> 10) & 255;
    float a = stats[o * 2 + 0], c = stats[o * 2 + 1];
    float4 xv = reinterpret_cast<const float4*>(x)[idx];
    ushort4 pv = reinterpret_cast<const ushort4*>(pre)[idx];
    float4 ov;
    ov.x = xv.x + bf2f(pv.x) * a + c;
    ov.y = xv.y + bf2f(pv.y) * a + c;
    ov.z = xv.z + bf2f(pv.z) * a + c;
    ov.w = xv.w + bf2f(pv.w) * a + c;
    reinterpret_cast<float4*>(out)[idx] = ov;
}

// ---------------- launch ----------------
extern "C" void kernel_launch(void* const* d_in, const int* in_sizes, int n_in,
                              void* d_out, int out_size, void* d_ws, size_t ws_size,
                              hipStream_t stream) {
    const float* x  = (const float*)d_in[0];
    const float* tw = (const float*)d_in[1];
    const float* tb = (const float*)d_in[2];
    const float* pw = (const float*)d_in[3];
    const float* pb = (const float*)d_in[4];
    const float* gw = (const float*)d_in[5];
    const float* gb = (const float*)d_in[6];
    const float* ow = (const float*)d_in[7];
    const float* ob = (const float*)d_in[8];
    const float* gamma = (const float*)d_in[9];
    const float* beta  = (const float*)d_in[10];

    char* ws = (char*)d_ws;
    const size_t WBF_OFF  = 0;                       // 196608
    const size_t OWBF_OFF = WBF_OFF + 196608;        // 65536
    const size_t XT_OFF   = OWBF_OFF + 65536;        // 16777216
    const size_t QT_OFF   = XT_OFF + 16777216;       // 8388608
    const size_t KT_OFF   = QT_OFF + 8388608;        // 8388608
    const size_t GV_OFF   = KT_OFF + 8388608;        // 8388608 (tiled)
    const size_t YT_OFF   = GV_OFF + 8388608;        // 8388608
    const size_t PRE_OFF  = YT_OFF + 8388608;        // 16777216 (bf16)
    const size_t PART_OFF = PRE_OFF + 16777216;      // 1048576
    const size_t ST_OFF   = PART_OFF + 1048576;      // 2048

    ushort* wbf  = (ushort*)(ws + WBF_OFF);
    ushort* owbf = (ushort*)(ws + OWBF_OFF);
    ushort* xt   = (ushort*)(ws + XT_OFF);
    ushort* qt   = (ushort*)(ws + QT_OFF);
    ushort* kt   = (ushort*)(ws + KT_OFF);
    ushort* gv   = (ushort*)(ws + GV_OFF);
    ushort* yt   = (ushort*)(ws + YT_OFF);
    ushort* pre  = (ushort*)(ws + PRE_OFF);
    float*  part = (float*)(ws + PART_OFF);
    float*  stats= (float*)(ws + ST_OFF);

    k_prep<<<384, 256, 0, stream>>>(tw, pw, gw, ow, wbf, owbf);
    k_transpose<<<dim3(64, 4, 8), 256, 0, stream>>>(x, xt);
    k_qkv<<<dim3(32, 3, 8), 256, 0, stream>>>(wbf, xt, tb, pb, gb, qt, kt, gv);
    k_attn<<<256, 256, 0, stream>>>(qt, kt, gv, yt);
    k_outconv<<<dim3(32, 2, 8), 256, 0, stream>>>(owbf, yt, ob, pre, part);
    k_stats<<<256, 256, 0, stream>>>(part, gamma, beta, stats);
    k_final<<<8192, 256, 0, stream>>>(x, pre, stats, (float*)d_out);
}

// Round 12
// 166.370 us; speedup vs baseline: 1.2874x; 1.2874x over previous
//
#include <hip/hip_runtime.h>
#include <hip/hip_bf16.h>

typedef __bf16 bf16x8 __attribute__((ext_vector_type(8)));
typedef float f32x4 __attribute__((ext_vector_type(4)));
typedef float f32x16 __attribute__((ext_vector_type(16)));

#define B_ 8
#define C_ 256
#define CI 128
#define N_ 4096

__device__ __forceinline__ float exp2fast(float x) {
    return __builtin_amdgcn_exp2f(x);   // v_exp_f32: 2^x
}
__device__ __forceinline__ ushort f2bf(float f) {
    union { float f; unsigned u; } v; v.f = f;
    unsigned r = v.u + 0x7fffu + ((v.u >> 16) & 1u);
    return (ushort)(r >> 16);
}
__device__ __forceinline__ float bf2f(ushort u) {
    union { unsigned u; float f; } v; v.u = ((unsigned)u) << 16;
    return v.f;
}
__device__ __forceinline__ unsigned cvtpk(float lo, float hi) {
    unsigned r;
    asm("v_cvt_pk_bf16_f32 %0, %1, %2" : "=v"(r) : "v"(lo), "v"(hi));
    return r;
}
__device__ __forceinline__ void plswap(unsigned& a, unsigned& b) {
    asm volatile("v_permlane32_swap_b32 %0, %1" : "+v"(a), "+v"(b));
}
__device__ __forceinline__ void gld16(const void* src, void* dst) {
    __builtin_amdgcn_global_load_lds(
        (const __attribute__((address_space(1))) unsigned*)src,
        (__attribute__((address_space(3))) unsigned*)dst, 16, 0, 0);
}

// ---------------- kernel 1: weight conversion ----------------
__global__ void k_prep(const float* __restrict__ tw, const float* __restrict__ pw,
                       const float* __restrict__ gw, const float* __restrict__ ow,
                       ushort* __restrict__ wbf, ushort* __restrict__ owbf) {
    int idx = blockIdx.x * 256 + threadIdx.x;
    if (idx < 384 * 256) {
        int i = idx >> 8, c = idx & 255;
        float v = (i < 128) ? tw[i * 256 + c]
                : (i < 256) ? pw[(i - 128) * 256 + c]
                            : gw[(i - 256) * 256 + c];
        wbf[idx] = f2bf(v);
    }
    if (idx < 256 * 128) owbf[idx] = f2bf(ow[idx]);
}

// ---------------- kernel 2: x -> xt[b][n][c] bf16 ----------------
__global__ __launch_bounds__(256) void k_transpose(const float* __restrict__ x,
                                                   ushort* __restrict__ xt) {
    __shared__ __align__(16) float tile[64][65];
    int b = blockIdx.z, c0 = blockIdx.y * 64, n0 = blockIdx.x * 64;
    int t = threadIdx.x;
    int cl = t >> 2, nc = (t & 3) * 16;
    const float* src = x + ((size_t)(b * 256 + c0 + cl)) * N_ + n0 + nc;
#pragma unroll
    for (int j = 0; j < 4; j++) {
        float4 v = *reinterpret_cast<const float4*>(src + 4 * j);
        tile[cl][nc + 4 * j + 0] = v.x;
        tile[cl][nc + 4 * j + 1] = v.y;
        tile[cl][nc + 4 * j + 2] = v.z;
        tile[cl][nc + 4 * j + 3] = v.w;
    }
    __syncthreads();
    int nl = t >> 2, cc = (t & 3) * 16;
    ushort* dst = xt + ((size_t)b * N_ + n0 + nl) * 256 + c0 + cc;
#pragma unroll
    for (int j = 0; j < 4; j++) {
        ushort4 o;
        o.x = f2bf(tile[cc + 4 * j + 0][nl]);
        o.y = f2bf(tile[cc + 4 * j + 1][nl]);
        o.z = f2bf(tile[cc + 4 * j + 2][nl]);
        o.w = f2bf(tile[cc + 4 * j + 3][nl]);
        *reinterpret_cast<ushort4*>(dst + 4 * j) = o;
    }
}

// ---------------- kernel 3: QKV GEMM ----------------
// it=0 -> theta*scale*log2e -> qt[n][c]; it=1 -> phi -> kt[n][c];
// it=2 -> g -> gvt TILED layout: [b][mt=n/32][chunk 0..511][16B] with
//   chunk(c, slot=(n%32)/8) = (c&7) | (slot<<3) | ((c>>3)<<5), elem = n%8.
__global__ __launch_bounds__(256) void k_qkv(const ushort* __restrict__ wbf,
                                             const ushort* __restrict__ xt,
                                             const float* __restrict__ tb,
                                             const float* __restrict__ pb,
                                             const float* __restrict__ gb,
                                             ushort* __restrict__ qt,
                                             ushort* __restrict__ kt,
                                             ushort* __restrict__ gv) {
    __shared__ __align__(16) ushort lt[4][64][72];
    int nt = blockIdx.x, it = blockIdx.y, b = blockIdx.z;
    int tid = threadIdx.x, w = tid >> 6, l = tid & 63, lr = l & 15, lg = l >> 4;
    int i_off = it * 128 + (w >> 1) * 64;
    int n_off = nt * 128 + (w & 1) * 64;
    const ushort* xb = xt + (size_t)b * N_ * 256;

    f32x4 acc[4][4];
#pragma unroll
    for (int i = 0; i < 4; i++)
#pragma unroll
        for (int j = 0; j < 4; j++) acc[i][j] = (f32x4)0.0f;

#pragma unroll
    for (int kc = 0; kc < 8; kc++) {
        int ko = kc * 32 + lg * 8;
        bf16x8 a[4], bb[4];
#pragma unroll
        for (int fi = 0; fi < 4; fi++)
            a[fi] = *reinterpret_cast<const bf16x8*>(wbf + (size_t)(i_off + fi * 16 + lr) * 256 + ko);
#pragma unroll
        for (int fn = 0; fn < 4; fn++)
            bb[fn] = *reinterpret_cast<const bf16x8*>(xb + (size_t)(n_off + fn * 16 + lr) * 256 + ko);
#pragma unroll
        for (int fi = 0; fi < 4; fi++)
#pragma unroll
            for (int fn = 0; fn < 4; fn++)
                acc[fi][fn] = __builtin_amdgcn_mfma_f32_16x16x32_bf16(a[fi], bb[fn], acc[fi][fn], 0, 0, 0);
    }

    const float* bias = (it == 0) ? tb : (it == 1) ? pb : gb;
    // fold 1/sqrt(128) * log2(e) into theta so attention can use exp2
    const float mul = (it == 0) ? (0.08838834764831845f * 1.4426950408889634f) : 1.0f;
    if (it == 2) {
        char* g = (char*)(gv + (size_t)b * CI * N_);   // tiled per batch: 128 tiles x 8192 B
#pragma unroll
        for (int fi = 0; fi < 4; fi++)
#pragma unroll
            for (int reg = 0; reg < 4; reg++) {
                int cl = (w >> 1) * 64 + fi * 16 + lg * 4 + reg;
                float bv = bias[cl];
                int cbyte = (cl & 7) * 16 + (cl >> 3) * 512;
#pragma unroll
                for (int fn = 0; fn < 4; fn++) {
                    int n = n_off + fn * 16 + lr;
                    size_t byte = (size_t)(n >> 5) * 8192 + cbyte
                                + ((n >> 3) & 3) * 128 + (n & 7) * 2;
                    *(ushort*)(g + byte) = f2bf(acc[fi][fn][reg] + bv);
                }
            }
    } else {
#pragma unroll
        for (int fi = 0; fi < 4; fi++)
#pragma unroll
            for (int reg = 0; reg < 4; reg++) {
                int il = fi * 16 + lg * 4 + reg;
                float bv = bias[(w >> 1) * 64 + il];
#pragma unroll
                for (int fn = 0; fn < 4; fn++)
                    lt[w][fn * 16 + lr][il] = f2bf((acc[fi][fn][reg] + bv) * mul);
            }
        __builtin_amdgcn_s_waitcnt(0);
        ushort* dst = ((it == 0) ? qt : kt) + (size_t)b * N_ * CI;
        ushort* drow = dst + (size_t)(n_off + l) * CI + (w >> 1) * 64;
#pragma unroll
        for (int cc = 0; cc < 8; cc++) {
            uint4 v = *reinterpret_cast<uint4*>(&lt[w][l][cc * 8]);
            *reinterpret_cast<uint4*>(drow + cc * 8) = v;
        }
    }
}

// ---------------- kernel 4: flash attention, 64 q-rows/wave, 2 blocks/CU ----------
// qt,kt: [b][n][128] (qt pre-scaled); gv: TILED (see k_qkv); yt: [b][n][128]
// 256 blocks x 256 threads, LDS EXACTLY 64KB -> 2 blocks/CU (r8-proven TLP) AND
// 2-chain K/V fragment reuse (r10's halved LDS traffic). launch_bounds(256,1):
// the (256,2) cap clamps VGPR to 128 and spills (r11 post-mortem); (256,1)
// gives 180 VGPR, no spill, and 2x180 <= 512/SIMD so 2 waves/SIMD still fit.
// Wave (p=w>>1, s=w&1): KV half p (64 iters of KVBLK=32), q-rows qb*128+s*64..+63
// as two 32-q chains. Merge publishes acc0/acc1 in TWO rounds through a 34816B
// scratch (stride 68 f32 = 17 granules, conflict-free) reusing dead K/V space.
__global__ __launch_bounds__(256, 1) void k_attn(const ushort* __restrict__ qt,
                                                 const ushort* __restrict__ kt,
                                                 const ushort* __restrict__ gv,
                                                 ushort* __restrict__ yt) {
    __shared__ __align__(16) char smem[65536];
    int bid = blockIdx.x;
    int b = bid & 7, qb = bid >> 3;  // batch -> XCD affinity
    int tid = threadIdx.x, w = tid >> 6, l = tid & 63;
    int p = w >> 1, s = w & 1;
    int l31 = l & 31, lh = l >> 5;
    const ushort* qtb = qt + (size_t)b * N_ * CI;
    const ushort* ktb = kt + (size_t)b * N_ * CI;
    const ushort* gvb = gv + (size_t)b * CI * N_;
    char* kbuf = smem + p * 16384;           // [buf][32 m][256 B]  XOR-swizzled
    char* vbuf = smem + 32768 + p * 16384;   // [buf][512 chunks of 16B] tiled image
    const int pbase = p * 2048;
    const int nq = qb * 128 + s * 64;
    const int q0 = nq + l31, q1 = nq + 32 + l31;
    const int swk = (l31 & 7) << 4;
    const int vrb = (l31 & 7) * 16 + lh * 128 + (l31 >> 3) * 512;  // + mk*256 + fc*2048

    // Q fragments for both 32-q chains
    bf16x8 qf0[8], qf1[8];
#pragma unroll
    for (int kc = 0; kc < 8; kc++) {
        qf0[kc] = *reinterpret_cast<const bf16x8*>(qtb + (size_t)q0 * CI + kc * 16 + lh * 8);
        qf1[kc] = *reinterpret_cast<const bf16x8*>(qtb + (size_t)q1 * CI + kc * 16 + lh * 8);
    }

    f32x16 acc0[4], acc1[4];
#pragma unroll
    for (int fc = 0; fc < 4; fc++) { acc0[fc] = (f32x16)0.0f; acc1[fc] = (f32x16)0.0f; }
    float lr0 = 0.f, lr1 = 0.f;

#define STAGE(t_, bi)                                                              \
    do {                                                                           \
        int m0_ = pbase + (t_) * 32;                                               \
        const char* ks_ = (const char*)(ktb + (size_t)m0_ * CI);                   \
        const char* vs_ = (const char*)gvb + (size_t)m0_ * 256;                    \
        char* kd_ = kbuf + (bi) * 8192;                                            \
        char* vd_ = vbuf + (bi) * 8192;                                            \
        _Pragma("unroll")                                                          \
        for (int i_ = 0; i_ < 4; ++i_) {                                           \
            int cc = i_ * 128 + s * 64 + l;                                        \
            int m_ = cc >> 4, hb = (cc & 15) << 4;                                 \
            gld16(ks_ + m_ * 256 + (hb ^ ((m_ & 7) << 4)), kd_ + cc * 16);         \
        }                                                                          \
        _Pragma("unroll")                                                          \
        for (int i_ = 0; i_ < 4; ++i_) {                                           \
            int cc = i_ * 128 + s * 64 + l;                                        \
            gld16(vs_ + cc * 16, vd_ + cc * 16);                                   \
        }                                                                          \
    } while (0)

    STAGE(0, 0);
    __syncthreads();

    for (int t = 0; t < 64; ++t) {
        int cur = t & 1;
        if (t < 63) STAGE(t + 1, cur ^ 1);
        const char* kbc = kbuf + cur * 8192;
        const char* vbc = vbuf + cur * 8192;

        // ---- QK^T: each kf read feeds both q-chains ----
        f32x16 S0 = (f32x16)0.0f, S1 = (f32x16)0.0f;
        __builtin_amdgcn_s_setprio(1);
#pragma unroll
        for (int kc = 0; kc < 8; kc++) {
            bf16x8 kf = *reinterpret_cast<const bf16x8*>(
                kbc + l31 * 256 + ((kc * 32 + lh * 16) ^ swk));
            S0 = __builtin_amdgcn_mfma_f32_32x32x16_bf16(kf, qf0[kc], S0, 0, 0, 0);
            S1 = __builtin_amdgcn_mfma_f32_32x32x16_bf16(kf, qf1[kc], S1, 0, 0, 0);
        }
        __builtin_amdgcn_s_setprio(0);

        // ---- softmax (no max tracking), chain 0 then chain 1 ----
        union { unsigned u[4]; bf16x8 v; } p00, p01, p10, p11;
        {
            float pv[16];
            float rs = 0.f;
#pragma unroll
            for (int r = 0; r < 16; r++) { pv[r] = exp2fast(S0[r]); rs += pv[r]; }
            lr0 += rs;
            unsigned u0 = cvtpk(pv[0], pv[1]),  u1 = cvtpk(pv[2], pv[3]);
            unsigned u2 = cvtpk(pv[4], pv[5]),  u3 = cvtpk(pv[6], pv[7]);
            unsigned u4 = cvtpk(pv[8], pv[9]),  u5 = cvtpk(pv[10], pv[11]);
            unsigned u6 = cvtpk(pv[12], pv[13]), u7 = cvtpk(pv[14], pv[15]);
            plswap(u0, u2); plswap(u1, u3); plswap(u4, u6); plswap(u5, u7);
            p00.u[0] = u0; p00.u[1] = u1; p00.u[2] = u2; p00.u[3] = u3;
            p01.u[0] = u4; p01.u[1] = u5; p01.u[2] = u6; p01.u[3] = u7;
        }
        {
            float pv[16];
            float rs = 0.f;
#pragma unroll
            for (int r = 0; r < 16; r++) { pv[r] = exp2fast(S1[r]); rs += pv[r]; }
            lr1 += rs;
            unsigned u0 = cvtpk(pv[0], pv[1]),  u1 = cvtpk(pv[2], pv[3]);
            unsigned u2 = cvtpk(pv[4], pv[5]),  u3 = cvtpk(pv[6], pv[7]);
            unsigned u4 = cvtpk(pv[8], pv[9]),  u5 = cvtpk(pv[10], pv[11]);
            unsigned u6 = cvtpk(pv[12], pv[13]), u7 = cvtpk(pv[14], pv[15]);
            plswap(u0, u2); plswap(u1, u3); plswap(u4, u6); plswap(u5, u7);
            p10.u[0] = u0; p10.u[1] = u1; p10.u[2] = u2; p10.u[3] = u3;
            p11.u[0] = u4; p11.u[1] = u5; p11.u[2] = u6; p11.u[3] = u7;
        }

        // ---- PV: each vf read feeds both q-chains ----
        __builtin_amdgcn_s_setprio(1);
#pragma unroll
        for (int mk = 0; mk < 2; mk++) {
            bf16x8 pf0 = mk ? p01.v : p00.v;
            bf16x8 pf1 = mk ? p11.v : p10.v;
#pragma unroll
            for (int fc = 0; fc < 4; fc++) {
                bf16x8 vf = *reinterpret_cast<const bf16x8*>(vbc + vrb + mk * 256 + fc * 2048);
                acc0[fc] = __builtin_amdgcn_mfma_f32_32x32x16_bf16(vf, pf0, acc0[fc], 0, 0, 0);
                acc1[fc] = __builtin_amdgcn_mfma_f32_32x32x16_bf16(vf, pf1, acc1[fc], 0, 0, 0);
            }
        }
        __builtin_amdgcn_s_setprio(0);
        __syncthreads();
    }
#undef STAGE

    // complete softmax denominators across the two lane-halves
    lr0 += __shfl_xor(lr0, 32);
    lr1 += __shfl_xor(lr1, 32);

    // ---- split-KV merge, TWO rounds (chain 0 then chain 1) through 34816B ----
    // pub: [2 s][64 lanes][68 f32] (17 x 16B granules -> conflict-free);
    // mlb: [2 s][64 q] at +34816.
    float* pub = (float*)smem;
    float* mlb = (float*)(smem + 34816);
    __syncthreads();   // all waves done with K/V buffers before reuse
    if (p == 0 && lh == 0) {
        mlb[s * 64 + l31] = lr0;
        mlb[s * 64 + 32 + l31] = lr1;
    }
    if (p == 0) {
        float* ab = pub + (size_t)(s * 64 + l) * 68;
#pragma unroll
        for (int fc = 0; fc < 4; fc++)
            *reinterpret_cast<f32x16*>(ab + fc * 16) = acc0[fc];
    }
    __syncthreads();
    if (p == 1) {
        float inv0 = 1.f / (lr0 + mlb[s * 64 + l31]);
        const float* ab = pub + (size_t)(s * 64 + l) * 68;
        ushort* yb0 = yt + ((size_t)b * N_ + q0) * CI;
#pragma unroll
        for (int fc = 0; fc < 4; fc++) {
            f32x16 a0 = *reinterpret_cast<const f32x16*>(ab + fc * 16);
#pragma unroll
            for (int rg = 0; rg < 4; rg++) {
                ushort4 o;
                o.x = f2bf((acc0[fc][rg * 4 + 0] + a0[rg * 4 + 0]) * inv0);
                o.y = f2bf((acc0[fc][rg * 4 + 1] + a0[rg * 4 + 1]) * inv0);
                o.z = f2bf((acc0[fc][rg * 4 + 2] + a0[rg * 4 + 2]) * inv0);
                o.w = f2bf((acc0[fc][rg * 4 + 3] + a0[rg * 4 + 3]) * inv0);
                *reinterpret_cast<ushort4*>(yb0 + fc * 32 + rg * 8 + lh * 4) = o;
            }
        }
    }
    __syncthreads();
    if (p == 0) {
        float* ab = pub + (size_t)(s * 64 + l) * 68;
#pragma unroll
        for (int fc = 0; fc < 4; fc++)
            *reinterpret_cast<f32x16*>(ab + fc * 16) = acc1[fc];
    }
    __syncthreads();
    if (p == 1) {
        float inv1 = 1.f / (lr1 + mlb[s * 64 + 32 + l31]);
        const float* ab = pub + (size_t)(s * 64 + l) * 68;
        ushort* yb1 = yt + ((size_t)b * N_ + q1) * CI;
#pragma unroll
        for (int fc = 0; fc < 4; fc++) {
            f32x16 a1 = *reinterpret_cast<const f32x16*>(ab + fc * 16);
#pragma unroll
            for (int rg = 0; rg < 4; rg++) {
                ushort4 o;
                o.x = f2bf((acc1[fc][rg * 4 + 0] + a1[rg * 4 + 0]) * inv1);
                o.y = f2bf((acc1[fc][rg * 4 + 1] + a1[rg * 4 + 1]) * inv1);
                o.z = f2bf((acc1[fc][rg * 4 + 2] + a1[rg * 4 + 2]) * inv1);
                o.w = f2bf((acc1[fc][rg * 4 + 3] + a1[rg * 4 + 3]) * inv1);
                *reinterpret_cast<ushort4*>(yb1 + fc * 32 + rg * 8 + lh * 4) = o;
            }
        }
    }
}

// ---------------- kernel 5: out conv + partial BN sums (pre in bf16) ----------------
__global__ __launch_bounds__(256) void k_outconv(const ushort* __restrict__ owbf,
                                                 const ushort* __restrict__ yt,
                                                 const float* __restrict__ ob,
                                                 ushort* __restrict__ pre,
                                                 float* __restrict__ part) {
    int nt = blockIdx.x, ot = blockIdx.y, b = blockIdx.z;
    int tid = threadIdx.x, w = tid >> 6, l = tid & 63, lr = l & 15, lg = l >> 4;
    int o_off = ot * 128 + (w >> 1) * 64;
    int n_off = nt * 128 + (w & 1) * 64;
    const ushort* yb = yt + (size_t)b * N_ * CI;

    f32x4 acc[4][4];
#pragma unroll
    for (int i = 0; i < 4; i++)
#pragma unroll
        for (int j = 0; j < 4; j++) acc[i][j] = (f32x4)0.0f;

#pragma unroll
    for (int kc = 0; kc < 4; kc++) {
        int ko = kc * 32 + lg * 8;
        bf16x8 a[4], bb[4];
#pragma unroll
        for (int fo = 0; fo < 4; fo++)
            a[fo] = *reinterpret_cast<const bf16x8*>(owbf + (size_t)(o_off + fo * 16 + lr) * CI + ko);
#pragma unroll
        for (int fn = 0; fn < 4; fn++)
            bb[fn] = *reinterpret_cast<const bf16x8*>(yb + (size_t)(n_off + fn * 16 + lr) * CI + ko);
#pragma unroll
        for (int fo = 0; fo < 4; fo++)
#pragma unroll
            for (int fn = 0; fn < 4; fn++)
                acc[fo][fn] = __builtin_amdgcn_mfma_f32_16x16x32_bf16(a[fo], bb[fn], acc[fo][fn], 0, 0, 0);
    }

    ushort* pb_ = pre + (size_t)b * C_ * N_;
#pragma unroll
    for (int fo = 0; fo < 4; fo++)
#pragma unroll
        for (int reg = 0; reg < 4; reg++) {
            int o = o_off + fo * 16 + lg * 4 + reg;
            float bv = ob[o];
            float s1 = 0.f, s2 = 0.f;
#pragma unroll
            for (int fn = 0; fn < 4; fn++) {
                float v = acc[fo][fn][reg] + bv;
                pb_[(size_t)o * N_ + n_off + fn * 16 + lr] = f2bf(v);
                s1 += v;
                s2 += v * v;
            }
#pragma unroll
            for (int d = 1; d < 16; d <<= 1) {
                s1 += __shfl_xor(s1, d);
                s2 += __shfl_xor(s2, d);
            }
            if (lr == 0) {
                int slot = (b * 32 + nt) * 2 + (w & 1);
                part[((size_t)o * 512 + slot) * 2 + 0] = s1;
                part[((size_t)o * 512 + slot) * 2 + 1] = s2;
            }
        }
}

// ---------------- kernel 6: reduce BN stats ----------------
__global__ void k_stats(const float* __restrict__ part, const float* __restrict__ gamma,
                        const float* __restrict__ beta, float* __restrict__ stats) {
    int o = blockIdx.x, t = threadIdx.x;
    __shared__ float r1[256], r2[256];
    float s1 = part[((size_t)o * 512 + t) * 2 + 0] + part[((size_t)o * 512 + t + 256) * 2 + 0];
    float s2 = part[((size_t)o * 512 + t) * 2 + 1] + part[((size_t)o * 512 + t + 256) * 2 + 1];
    r1[t] = s1; r2[t] = s2;
    __syncthreads();
    for (int s = 128; s > 0; s >>= 1) {
        if (t < s) { r1[t] += r1[t + s]; r2[t] += r2[t + s]; }
        __syncthreads();
    }
    if (t == 0) {
        float cnt = 1.f / (float)(B_ * N_);
        float mean = r1[0] * cnt;
        float var = r2[0] * cnt - mean * mean;
        float inv = rsqrtf(var + 1e-5f);
        float a = gamma[o] * inv;
        stats[o * 2 + 0] = a;
        stats[o * 2 + 1] = beta[o] - mean * a;
    }
}

// ---------------- kernel 7: finalize ----------------
__global__ void k_final(const float* __restrict__ x, const ushort* __restrict__ pre,
                        const float* __restrict__ stats, float* __restrict__ out) {
    int idx = blockIdx.x * 256 + threadIdx.x;  // 4 elems each
    int o = (idx >> 10) & 255;
    float a = stats[o * 2 + 0], c = stats[o * 2 + 1];
    float4 xv = reinterpret_cast<const float4*>(x)[idx];
    ushort4 pv = reinterpret_cast<const ushort4*>(pre)[idx];
    float4 ov;
    ov.x = xv.x + bf2f(pv.x) * a + c;
    ov.y = xv.y + bf2f(pv.y) * a + c;
    ov.z = xv.z + bf2f(pv.z) * a + c;
    ov.w = xv.w + bf2f(pv.w) * a + c;
    reinterpret_cast<float4*>(out)[idx] = ov;
}

// ---------------- launch ----------------
extern "C" void kernel_launch(void* const* d_in, const int* in_sizes, int n_in,
                              void* d_out, int out_size, void* d_ws, size_t ws_size,
                              hipStream_t stream) {
    const float* x  = (const float*)d_in[0];
    const float* tw = (const float*)d_in[1];
    const float* tb = (const float*)d_in[2];
    const float* pw = (const float*)d_in[3];
    const float* pb = (const float*)d_in[4];
    const float* gw = (const float*)d_in[5];
    const float* gb = (const float*)d_in[6];
    const float* ow = (const float*)d_in[7];
    const float* ob = (const float*)d_in[8];
    const float* gamma = (const float*)d_in[9];
    const float* beta  = (const float*)d_in[10];

    char* ws = (char*)d_ws;
    const size_t WBF_OFF  = 0;                       // 196608
    const size_t OWBF_OFF = WBF_OFF + 196608;        // 65536
    const size_t XT_OFF   = OWBF_OFF + 65536;        // 16777216
    const size_t QT_OFF   = XT_OFF + 16777216;       // 8388608
    const size_t KT_OFF   = QT_OFF + 8388608;        // 8388608
    const size_t GV_OFF   = KT_OFF + 8388608;        // 8388608 (tiled)
    const size_t YT_OFF   = GV_OFF + 8388608;        // 8388608
    const size_t PRE_OFF  = YT_OFF + 8388608;        // 16777216 (bf16)
    const size_t PART_OFF = PRE_OFF + 16777216;      // 1048576
    const size_t ST_OFF   = PART_OFF + 1048576;      // 2048

    ushort* wbf  = (ushort*)(ws + WBF_OFF);
    ushort* owbf = (ushort*)(ws + OWBF_OFF);
    ushort* xt   = (ushort*)(ws + XT_OFF);
    ushort* qt   = (ushort*)(ws + QT_OFF);
    ushort* kt   = (ushort*)(ws + KT_OFF);
    ushort* gv   = (ushort*)(ws + GV_OFF);
    ushort* yt   = (ushort*)(ws + YT_OFF);
    ushort* pre  = (ushort*)(ws + PRE_OFF);
    float*  part = (float*)(ws + PART_OFF);
    float*  stats= (float*)(ws + ST_OFF);

    k_prep<<<384, 256, 0, stream>>>(tw, pw, gw, ow, wbf, owbf);
    k_transpose<<<dim3(64, 4, 8), 256, 0, stream>>>(x, xt);
    k_qkv<<<dim3(32, 3, 8), 256, 0, stream>>>(wbf, xt, tb, pb, gb, qt, kt, gv);
    k_attn<<<256, 256, 0, stream>>>(qt, kt, gv, yt);
    k_outconv<<<dim3(32, 2, 8), 256, 0, stream>>>(owbf, yt, ob, pre, part);
    k_stats<<<256, 256, 0, stream>>>(part, gamma, beta, stats);
    k_final<<<8192, 256, 0, stream>>>(x, pre, stats, (float*)d_out);
}